// Round 2
// baseline (91.651 us; speedup 1.0000x reference)
//
#include <hip/hip_runtime.h>

#define NUM_FRAMES 1000
#define NUM_CAM    8
#define FR_STRIDE  9   // odd stride -> random frame rows spread over all 32 banks
#define CAM_STRIDE 9   // row stride; cam-to-cam stride 27 -> 8 distinct banks

__device__ __forceinline__ float softplus_acc(float x) {
    return (x > 20.0f) ? x : log1pf(expf(x));
}

// Per-pixel ISP math. Tables:
//  s_frame[f*9]  = {er=exp(e+cp0), eg=exp(e), eb=exp(e+cp1), o0..o5}
//  s_cam[(cam*3+ch)*9] = {cx, cy, a2, a3, a4, k1, k2, k3, k4}
__device__ __forceinline__ void ppisp_px(
    float r, float g, float b, float px, float py,
    int cam, int frm, float invw, float invh,
    const float* __restrict__ s_frame, const float* __restrict__ s_cam,
    float* o)
{
    const float* fr = s_frame + frm * FR_STRIDE;
    float er = fr[0], eg = fr[1], eb = fr[2];
    float o0 = fr[3], o1 = fr[4], o2 = fr[5];
    float o3 = fr[6], o4 = fr[7], o5 = fr[8];

    float nx = px * invw - 0.5f;
    float ny = py * invh - 0.5f;

    const float* cc = s_cam + cam * (3 * CAM_STRIDE);

    // exposure * per-channel color exp (commutes with vignetting scale)
    float xin0 = r * er, xin1 = g * eg, xin2 = b * eb;
    float xv[3];
#pragma unroll
    for (int ch = 0; ch < 3; ++ch) {
        const float* c = cc + ch * CAM_STRIDE;
        float dx = nx - c[0];
        float dy = ny - c[1];
        float r2 = dx * dx + dy * dy;
        float r4 = r2 * r2;
        float r6 = r4 * r2;
        float vg = 1.0f + c[2] * r2 + c[3] * r4 + c[4] * r6;
        float xi = (ch == 0) ? xin0 : ((ch == 1) ? xin1 : xin2);
        xv[ch] = xi * vg;
    }

    float m[3];
    m[0] = xv[0] + o0 * xv[1] + o1 * xv[2];
    m[1] = o2 * xv[0] + xv[1] + o3 * xv[2];
    m[2] = o4 * xv[0] + o5 * xv[1] + xv[2];

#pragma unroll
    for (int ch = 0; ch < 3; ++ch) {
        const float* c = cc + ch * CAM_STRIDE;
        float k1 = c[5], k2 = c[6], k3 = c[7], k4 = c[8];
        float xg  = exp2f(k3 * log2f(fmaxf(m[ch], 1e-6f)));
        float den = __builtin_fmaf(k1 - 1.0f, xg, k2);
        o[ch] = k1 * xg * __builtin_amdgcn_rcpf(den) + k4;
    }
}

__global__ __launch_bounds__(256, 4)
void ppisp_kernel(const float* __restrict__ rgb,
                  const float* __restrict__ pc,
                  const int*   __restrict__ cam_idx,
                  const int*   __restrict__ frm_idx,
                  const float* __restrict__ expo,
                  const float* __restrict__ vigp,
                  const float* __restrict__ cp,
                  const float* __restrict__ crf,
                  const int*   __restrict__ resw_p,
                  const int*   __restrict__ resh_p,
                  float* __restrict__ out,
                  int n)
{
    __shared__ float s_frame[NUM_FRAMES * FR_STRIDE];
    __shared__ float s_cam[NUM_CAM * 3 * CAM_STRIDE];

    // ---- build frame table (hoists all frame-dependent exps) ----
    for (int f = threadIdx.x; f < NUM_FRAMES; f += blockDim.x) {
        float e = expo[f];
        const float* c = cp + f * 8;
        float* d = s_frame + f * FR_STRIDE;
        d[0] = expf(e + c[0]);   // er
        d[1] = expf(e);          // eg
        d[2] = expf(e + c[1]);   // eb
        d[3] = c[2]; d[4] = c[3]; d[5] = c[4];
        d[6] = c[5]; d[7] = c[6]; d[8] = c[7];
    }
    // ---- build camera table (hoists softplus) ----
    for (int rr = threadIdx.x; rr < NUM_CAM * 3; rr += blockDim.x) {
        const float* v = vigp + rr * 5;
        const float* k = crf + rr * 4;
        float* d = s_cam + rr * CAM_STRIDE;
        d[0] = v[0]; d[1] = v[1]; d[2] = v[2]; d[3] = v[3]; d[4] = v[4];
        d[5] = 0.3f + softplus_acc(k[0]);
        d[6] = 0.3f + softplus_acc(k[1]);
        d[7] = 0.1f + softplus_acc(k[2]);
        d[8] = k[3];
    }
    __syncthreads();

    float invw = 1.0f / (float)(*resw_p);
    float invh = 1.0f / (float)(*resh_p);

    const float4* rgb4 = (const float4*)rgb;
    const float4* pc4  = (const float4*)pc;
    const int4*   cam4 = (const int4*)cam_idx;
    const int4*   frm4 = (const int4*)frm_idx;
    float4* out4 = (float4*)out;

    int ngroups = n >> 2;
    int stride = gridDim.x * blockDim.x;
    for (int gi = blockIdx.x * blockDim.x + threadIdx.x; gi < ngroups; gi += stride) {
        float4 r0 = rgb4[gi * 3 + 0];
        float4 r1 = rgb4[gi * 3 + 1];
        float4 r2 = rgb4[gi * 3 + 2];
        float4 p0 = pc4[gi * 2 + 0];
        float4 p1 = pc4[gi * 2 + 1];
        int4 cm = cam4[gi];
        int4 fm = frm4[gi];

        float a[3], bb[3], c[3], d[3];
        ppisp_px(r0.x, r0.y, r0.z, p0.x, p0.y, cm.x, fm.x, invw, invh, s_frame, s_cam, a);
        ppisp_px(r0.w, r1.x, r1.y, p0.z, p0.w, cm.y, fm.y, invw, invh, s_frame, s_cam, bb);
        ppisp_px(r1.z, r1.w, r2.x, p1.x, p1.y, cm.z, fm.z, invw, invh, s_frame, s_cam, c);
        ppisp_px(r2.y, r2.z, r2.w, p1.z, p1.w, cm.w, fm.w, invw, invh, s_frame, s_cam, d);

        out4[gi * 3 + 0] = make_float4(a[0], a[1], a[2], bb[0]);
        out4[gi * 3 + 1] = make_float4(bb[1], bb[2], c[0], c[1]);
        out4[gi * 3 + 2] = make_float4(c[2], d[0], d[1], d[2]);
    }

    // tail (n not divisible by 4) — negligible work
    int rem_start = ngroups << 2;
    int nrem = n - rem_start;
    if (blockIdx.x == 0 && (int)threadIdx.x < nrem) {
        int i = rem_start + threadIdx.x;
        float o[3];
        ppisp_px(rgb[i * 3], rgb[i * 3 + 1], rgb[i * 3 + 2],
                 pc[i * 2], pc[i * 2 + 1],
                 cam_idx[i], frm_idx[i], invw, invh, s_frame, s_cam, o);
        out[i * 3 + 0] = o[0];
        out[i * 3 + 1] = o[1];
        out[i * 3 + 2] = o[2];
    }
}

extern "C" void kernel_launch(void* const* d_in, const int* in_sizes, int n_in,
                              void* d_out, int out_size, void* d_ws, size_t ws_size,
                              hipStream_t stream)
{
    const float* rgb  = (const float*)d_in[0];
    const float* pc   = (const float*)d_in[1];
    const int*   cam  = (const int*)d_in[2];
    const int*   frm  = (const int*)d_in[3];
    const float* expo = (const float*)d_in[4];
    const float* vigp = (const float*)d_in[5];
    const float* cp   = (const float*)d_in[6];
    const float* crf  = (const float*)d_in[7];
    const int*   resw = (const int*)d_in[8];
    const int*   resh = (const int*)d_in[9];
    float* out = (float*)d_out;

    int n = in_sizes[2];   // number of pixels (camera_idcs count)

    int ngroups = (n + 3) / 4;
    int blocks = (ngroups + 255) / 256;
    if (blocks > 2048) blocks = 2048;

    ppisp_kernel<<<dim3(blocks), dim3(256), 0, stream>>>(
        rgb, pc, cam, frm, expo, vigp, cp, crf, resw, resh, out, n);
}